// Round 1
// baseline (4745.243 us; speedup 1.0000x reference)
//
#include <hip/hip_runtime.h>
#include <math.h>

#define D_MODEL 1024
#define N_HEADS 16
#define D_HEAD  64
#define B_SZ    2
#define T_SEQ   2048

// ---------------------------------------------------------------------------
// Tiled fp32 GEMM + bias. C = A[M,K] @ W[K,N] + bias[N]
// mode 0: C[m*N + n]                       (plain row-major, used for O-proj)
// mode 1: C[((b*H + h)*T + t)*Dh + d]      (scatter to [B*H, T, Dh] for QKV)
// 32x32 tile, 256 threads, each thread computes 4 outputs (rows 8 apart).
// ---------------------------------------------------------------------------
__global__ __launch_bounds__(256) void gemm_bias_kernel(
    const float* __restrict__ A, const float* __restrict__ W,
    const float* __restrict__ bias, float* __restrict__ C,
    int M, int N, int K, int mode)
{
  __shared__ float As[32][33];   // +1 pad: break stride-32 bank aliasing
  __shared__ float Ws[32][33];

  const int tx = threadIdx.x & 31;   // tile col
  const int ty = threadIdx.x >> 5;   // 0..7
  const int row0 = blockIdx.x * 32;
  const int col0 = blockIdx.y * 32;

  float acc[4] = {0.f, 0.f, 0.f, 0.f};

  for (int k0 = 0; k0 < K; k0 += 32) {
    #pragma unroll
    for (int i = 0; i < 4; i++) {
      int r = ty + i * 8;
      As[r][tx] = A[(size_t)(row0 + r) * K + k0 + tx];
      Ws[r][tx] = W[(size_t)(k0 + r) * N + col0 + tx];
    }
    __syncthreads();
    #pragma unroll
    for (int kk = 0; kk < 32; kk++) {
      float w = Ws[kk][tx];
      #pragma unroll
      for (int i = 0; i < 4; i++) {
        acc[i] += As[ty + i * 8][kk] * w;
      }
    }
    __syncthreads();
  }

  const float bv = bias[col0 + tx];
  #pragma unroll
  for (int i = 0; i < 4; i++) {
    int m = row0 + ty + i * 8;
    int n = col0 + tx;
    float val = acc[i] + bv;
    if (mode == 0) {
      C[(size_t)m * N + n] = val;
    } else {
      int b = m / T_SEQ, t = m % T_SEQ;
      int h = n / D_HEAD, d = n % D_HEAD;
      C[((size_t)(b * N_HEADS + h) * T_SEQ + t) * D_HEAD + d] = val;
    }
  }
}

// ---------------------------------------------------------------------------
// Flash attention (causal), fp32.
// Q,K,V: [B*H, T, Dh]. Out: [B, T, H*Dh] (row-major [4096, 1024]).
// Grid: (T/BQ, B*H). Block: 256 threads.
// Thread t owns Q-row r = t>>2 and dim group g = t&3 (16 dims), accumulating
// o[16] in registers; m/l per row computed redundantly by the 4 group threads.
// ---------------------------------------------------------------------------
#define BQ 64
#define BK 64

__global__ __launch_bounds__(256) void flash_kernel(
    const float* __restrict__ Q, const float* __restrict__ K,
    const float* __restrict__ V, float* __restrict__ Out)
{
  const int bh = blockIdx.y;
  const int q0 = blockIdx.x * BQ;
  const int b  = bh / N_HEADS;
  const int h  = bh % N_HEADS;

  const float* Qb = Q + (size_t)bh * T_SEQ * D_HEAD;
  const float* Kb = K + (size_t)bh * T_SEQ * D_HEAD;
  const float* Vb = V + (size_t)bh * T_SEQ * D_HEAD;

  __shared__ float Qs[BQ][D_HEAD + 1];  // +1 pad: row stride 65 → conflict-free
  __shared__ float Ks[BK][D_HEAD + 1];
  __shared__ float Vs[BK][D_HEAD + 1];
  __shared__ float Ss[BQ][BK + 1];

  const int tid = threadIdx.x;
  const int r   = tid >> 2;       // Q row within tile, 0..63
  const int g   = tid & 3;        // dim group, 0..3
  const float scale = 0.125f;     // 1/sqrt(64)

  // Load Q tile (coalesced: consecutive tids -> consecutive addresses)
  #pragma unroll
  for (int i = 0; i < 16; i++) {
    int idx = i * 256 + tid;
    int row = idx >> 6, col = idx & 63;
    Qs[row][col] = Qb[(size_t)(q0 + row) * D_HEAD + col];
  }
  __syncthreads();

  float o[16];
  #pragma unroll
  for (int i = 0; i < 16; i++) o[i] = 0.f;
  float m = -INFINITY;
  float l = 0.f;

  for (int j0 = 0; j0 <= q0; j0 += BK) {
    // Load K/V tiles
    #pragma unroll
    for (int i = 0; i < 16; i++) {
      int idx = i * 256 + tid;
      int row = idx >> 6, col = idx & 63;
      Ks[row][col] = Kb[(size_t)(j0 + row) * D_HEAD + col];
      Vs[row][col] = Vb[(size_t)(j0 + row) * D_HEAD + col];
    }
    __syncthreads();

    // S = Q K^T for this tile; thread computes 16 entries of its row
    #pragma unroll
    for (int jj = 0; jj < 16; jj++) {
      int j = g * 16 + jj;
      float s = 0.f;
      #pragma unroll
      for (int kk = 0; kk < D_HEAD; kk++) {
        s += Qs[r][kk] * Ks[j][kk];
      }
      s *= scale;
      if (j0 + j > q0 + r) s = -INFINITY;   // causal mask
      Ss[r][j] = s;
    }
    __syncthreads();

    // Online softmax + PV accumulate (4 threads per row, redundant m/l)
    float mnew = m;
    #pragma unroll
    for (int j = 0; j < BK; j++) mnew = fmaxf(mnew, Ss[r][j]);
    float alpha = expf(m - mnew);   // m=-inf first tile -> exp(-inf)=0, safe
    l *= alpha;
    #pragma unroll
    for (int i = 0; i < 16; i++) o[i] *= alpha;
    for (int j = 0; j < BK; j++) {
      float p = expf(Ss[r][j] - mnew);
      l += p;
      #pragma unroll
      for (int i = 0; i < 16; i++) {
        o[i] += p * Vs[j][g * 16 + i];
      }
    }
    m = mnew;
    __syncthreads();   // Ss/Ks/Vs reads done before next tile overwrites
  }

  // Write O: Out[b*T + (q0+r)][h*64 + g*16 + i]
  const float inv_l = 1.f / l;
  const size_t orow = (size_t)(b * T_SEQ + q0 + r) * D_MODEL + h * D_HEAD + g * 16;
  #pragma unroll
  for (int i = 0; i < 16; i++) {
    Out[orow + i] = o[i] * inv_l;
  }
}

// ---------------------------------------------------------------------------
extern "C" void kernel_launch(void* const* d_in, const int* in_sizes, int n_in,
                              void* d_out, int out_size, void* d_ws, size_t ws_size,
                              hipStream_t stream) {
  (void)in_sizes; (void)n_in; (void)out_size; (void)ws_size;

  const float* x  = (const float*)d_in[0];
  const float* wq = (const float*)d_in[1];
  const float* bq = (const float*)d_in[2];
  const float* wk = (const float*)d_in[3];
  const float* bk = (const float*)d_in[4];
  const float* wv = (const float*)d_in[5];
  const float* bv = (const float*)d_in[6];
  const float* wo = (const float*)d_in[7];
  const float* bo = (const float*)d_in[8];
  float* out = (float*)d_out;

  const int M = B_SZ * T_SEQ;   // 4096
  const int N = D_MODEL;        // 1024
  const int K = D_MODEL;        // 1024

  float* q    = (float*)d_ws;                 // [B*H, T, Dh] 16 MiB
  float* k    = q + (size_t)M * N;            // 16 MiB
  float* v    = k + (size_t)M * N;            // 16 MiB
  float* attn = v + (size_t)M * N;            // [M, N] 16 MiB

  dim3 gblock(256);
  dim3 ggrid(M / 32, N / 32);
  gemm_bias_kernel<<<ggrid, gblock, 0, stream>>>(x, wq, bq, q, M, N, K, 1);
  gemm_bias_kernel<<<ggrid, gblock, 0, stream>>>(x, wk, bk, k, M, N, K, 1);
  gemm_bias_kernel<<<ggrid, gblock, 0, stream>>>(x, wv, bv, v, M, N, K, 1);

  dim3 fgrid(T_SEQ / BQ, B_SZ * N_HEADS);
  flash_kernel<<<fgrid, dim3(256), 0, stream>>>(q, k, v, attn);

  gemm_bias_kernel<<<ggrid, gblock, 0, stream>>>(attn, wo, bo, out, M, N, K, 0);
}

// Round 2
// 1583.014 us; speedup vs baseline: 2.9976x; 2.9976x over previous
//
#include <hip/hip_runtime.h>
#include <math.h>
#include <string.h>

#define D_MODEL 1024
#define N_HEADS 16
#define D_HEAD  64
#define B_SZ    2
#define T_SEQ   2048

typedef short bf16x8 __attribute__((ext_vector_type(8)));
typedef float f32x4  __attribute__((ext_vector_type(4)));

// fp32 -> bf16 (RNE), no dependence on __hip_bfloat16 internals
__device__ __forceinline__ unsigned short f2bf(float f) {
  union { float f; unsigned u; } v; v.f = f;
  unsigned r = v.u + 0x7FFFu + ((v.u >> 16) & 1u);
  return (unsigned short)(r >> 16);
}

// ---------------------------------------------------------------------------
// Tiled fp32 GEMM + bias. C = A[M,K] @ W[K,N] + bias[N]
// mode 0: fp32 C[m*N + n]                     (row-major, O-projection)
// mode 1: bf16 C[((b*H + h)*T + t)*Dh + d]    (scatter to [B*H, T, Dh] q/k/v)
// ---------------------------------------------------------------------------
__global__ __launch_bounds__(256) void gemm_bias_kernel(
    const float* __restrict__ A, const float* __restrict__ W,
    const float* __restrict__ bias, void* __restrict__ C,
    int M, int N, int K, int mode)
{
  __shared__ float As[32][33];
  __shared__ float Ws[32][33];

  const int tx = threadIdx.x & 31;
  const int ty = threadIdx.x >> 5;
  const int row0 = blockIdx.x * 32;
  const int col0 = blockIdx.y * 32;

  float acc[4] = {0.f, 0.f, 0.f, 0.f};

  for (int k0 = 0; k0 < K; k0 += 32) {
    #pragma unroll
    for (int i = 0; i < 4; i++) {
      int r = ty + i * 8;
      As[r][tx] = A[(size_t)(row0 + r) * K + k0 + tx];
      Ws[r][tx] = W[(size_t)(k0 + r) * N + col0 + tx];
    }
    __syncthreads();
    #pragma unroll
    for (int kk = 0; kk < 32; kk++) {
      float w = Ws[kk][tx];
      #pragma unroll
      for (int i = 0; i < 4; i++) acc[i] += As[ty + i * 8][kk] * w;
    }
    __syncthreads();
  }

  const float bv = bias[col0 + tx];
  #pragma unroll
  for (int i = 0; i < 4; i++) {
    int m = row0 + ty + i * 8;
    int n = col0 + tx;
    float val = acc[i] + bv;
    if (mode == 0) {
      ((float*)C)[(size_t)m * N + n] = val;
    } else {
      int b = m / T_SEQ, t = m % T_SEQ;
      int h = n / D_HEAD, d = n % D_HEAD;
      ((unsigned short*)C)[((size_t)(b * N_HEADS + h) * T_SEQ + t) * D_HEAD + d] = f2bf(val);
    }
  }
}

// ---------------------------------------------------------------------------
// MFMA flash attention (causal), bf16 inputs, fp32 softmax/accum.
// Q,K,V: bf16 [B*H, T, 64]. Out: fp32 [B, T, H*64].
// Grid (T/64, B*H), block 256 = 4 waves; wave w owns Q rows q0+w*16 .. +15.
// mfma_f32_16x16x32_bf16:
//   A frag: lane holds A[m=lane&15][k=quad*8+j], j=0..7   (one b128 from LDS)
//   B frag: lane holds B[k=quad*8+j][n=lane&15]
//   C/D:    lane reg i -> row=quad*4+i, col=lane&15
// ---------------------------------------------------------------------------
#define LDP 72   // LDS row stride in bf16 elems: 144 B = 9*16 -> b128-aligned, banks spread

__global__ __launch_bounds__(256) void flash_kernel(
    const unsigned short* __restrict__ Q, const unsigned short* __restrict__ K,
    const unsigned short* __restrict__ V, float* __restrict__ Out)
{
  const int bh = blockIdx.y;
  const int q0 = blockIdx.x * 64;
  const int b  = bh / N_HEADS;
  const int h  = bh % N_HEADS;

  const unsigned short* Qb = Q + (size_t)bh * T_SEQ * D_HEAD;
  const unsigned short* Kb = K + (size_t)bh * T_SEQ * D_HEAD;
  const unsigned short* Vb = V + (size_t)bh * T_SEQ * D_HEAD;

  __shared__ __align__(16) unsigned short Qs[64][LDP];
  __shared__ __align__(16) unsigned short Ks[64][LDP];
  __shared__ __align__(16) unsigned short Vt[64][LDP];   // Vt[d][kv]
  __shared__ __align__(16) unsigned short Ps[4][16][LDP];

  const int tid  = threadIdx.x;
  const int wv   = tid >> 6;
  const int lane = tid & 63;
  const int lr   = lane & 15;
  const int quad = lane >> 4;

  // ---- stage Q (once): 64 rows x 64 bf16, 16B per thread-chunk, 2 chunks ----
  #pragma unroll
  for (int it = 0; it < 2; it++) {
    int t = tid + it * 256;          // 0..511
    int row = t >> 3, c8 = (t & 7) * 8;
    *(uint4*)&Qs[row][c8] = *(const uint4*)&Qb[(size_t)(q0 + row) * D_HEAD + c8];
  }
  __syncthreads();

  // Q fragments are loop-invariant
  const bf16x8 aQ0 = *(const bf16x8*)&Qs[wv * 16 + lr][quad * 8];
  const bf16x8 aQ1 = *(const bf16x8*)&Qs[wv * 16 + lr][32 + quad * 8];

  f32x4 oacc[4];
  #pragma unroll
  for (int nt = 0; nt < 4; nt++) oacc[nt] = (f32x4){0.f, 0.f, 0.f, 0.f};
  float m_i[4] = {-INFINITY, -INFINITY, -INFINITY, -INFINITY};
  float l_i[4] = {0.f, 0.f, 0.f, 0.f};

  const float SCL2 = 0.125f * 1.44269504f;   // scale * log2(e): softmax in exp2 domain

  for (int j0 = 0; j0 <= q0; j0 += 64) {
    __syncthreads();   // all waves done reading previous Ks/Vt

    // ---- stage K tile (row-major) + V tile (transposed) ----
    #pragma unroll
    for (int it = 0; it < 2; it++) {
      int t = tid + it * 256;
      int row = t >> 3, c8 = (t & 7) * 8;
      *(uint4*)&Ks[row][c8] = *(const uint4*)&Kb[(size_t)(j0 + row) * D_HEAD + c8];
      union { uint4 u; unsigned short s[8]; } vv;
      vv.u = *(const uint4*)&Vb[(size_t)(j0 + row) * D_HEAD + c8];
      #pragma unroll
      for (int i = 0; i < 8; i++) Vt[c8 + i][row] = vv.s[i];
    }
    __syncthreads();

    // ---- S = Q K^T (16 q-rows x 64 kv), fp32 accum ----
    f32x4 sacc[4];
    #pragma unroll
    for (int nt = 0; nt < 4; nt++) {
      bf16x8 b0 = *(const bf16x8*)&Ks[nt * 16 + lr][quad * 8];
      bf16x8 b1 = *(const bf16x8*)&Ks[nt * 16 + lr][32 + quad * 8];
      f32x4 c = (f32x4){0.f, 0.f, 0.f, 0.f};
      c = __builtin_amdgcn_mfma_f32_16x16x32_bf16(aQ0, b0, c, 0, 0, 0);
      c = __builtin_amdgcn_mfma_f32_16x16x32_bf16(aQ1, b1, c, 0, 0, 0);
      sacc[nt] = c;
    }

    // ---- online softmax (z = s*scale*log2e domain) ----
    #pragma unroll
    for (int i = 0; i < 4; i++) {
      const int qrow = q0 + wv * 16 + quad * 4 + i;
      float z[4];
      float rm = -INFINITY;
      #pragma unroll
      for (int nt = 0; nt < 4; nt++) {
        float zz = sacc[nt][i] * SCL2;
        int kvc = j0 + nt * 16 + lr;
        zz = (kvc <= qrow) ? zz : -INFINITY;
        z[nt] = zz;
        rm = fmaxf(rm, zz);
      }
      rm = fmaxf(rm, __shfl_xor(rm, 1));
      rm = fmaxf(rm, __shfl_xor(rm, 2));
      rm = fmaxf(rm, __shfl_xor(rm, 4));
      rm = fmaxf(rm, __shfl_xor(rm, 8));
      const float mn = fmaxf(m_i[i], rm);
      const float alpha = exp2f(m_i[i] - mn);   // exp2(-inf)=0 on first tile
      float rs = 0.f;
      #pragma unroll
      for (int nt = 0; nt < 4; nt++) {
        float p = exp2f(z[nt] - mn);
        rs += p;
        Ps[wv][quad * 4 + i][nt * 16 + lr] = f2bf(p);
      }
      rs += __shfl_xor(rs, 1);
      rs += __shfl_xor(rs, 2);
      rs += __shfl_xor(rs, 4);
      rs += __shfl_xor(rs, 8);
      l_i[i] = l_i[i] * alpha + rs;
      m_i[i] = mn;
      #pragma unroll
      for (int nt = 0; nt < 4; nt++) oacc[nt][i] *= alpha;
    }

    // wave-local fence: Ps writes (this wave's lanes) -> Ps reads (other lanes, same wave)
    asm volatile("s_waitcnt lgkmcnt(0)" ::: "memory");

    // ---- O += P V ----
    const bf16x8 aP0 = *(const bf16x8*)&Ps[wv][lr][quad * 8];
    const bf16x8 aP1 = *(const bf16x8*)&Ps[wv][lr][32 + quad * 8];
    #pragma unroll
    for (int nt = 0; nt < 4; nt++) {
      bf16x8 b0 = *(const bf16x8*)&Vt[nt * 16 + lr][quad * 8];
      bf16x8 b1 = *(const bf16x8*)&Vt[nt * 16 + lr][32 + quad * 8];
      oacc[nt] = __builtin_amdgcn_mfma_f32_16x16x32_bf16(aP0, b0, oacc[nt], 0, 0, 0);
      oacc[nt] = __builtin_amdgcn_mfma_f32_16x16x32_bf16(aP1, b1, oacc[nt], 0, 0, 0);
    }
  }

  // ---- epilogue: Out[b*T + q][h*64 + d] = O / l ----
  float invl[4];
  #pragma unroll
  for (int i = 0; i < 4; i++) invl[i] = 1.f / l_i[i];
  #pragma unroll
  for (int nt = 0; nt < 4; nt++) {
    const int d = nt * 16 + lr;
    #pragma unroll
    for (int i = 0; i < 4; i++) {
      const int q = q0 + wv * 16 + quad * 4 + i;
      Out[(size_t)(b * T_SEQ + q) * D_MODEL + h * D_HEAD + d] = oacc[nt][i] * invl[i];
    }
  }
}

// ---------------------------------------------------------------------------
extern "C" void kernel_launch(void* const* d_in, const int* in_sizes, int n_in,
                              void* d_out, int out_size, void* d_ws, size_t ws_size,
                              hipStream_t stream) {
  (void)in_sizes; (void)n_in; (void)out_size; (void)ws_size;

  const float* x  = (const float*)d_in[0];
  const float* wq = (const float*)d_in[1];
  const float* bq = (const float*)d_in[2];
  const float* wk = (const float*)d_in[3];
  const float* bk = (const float*)d_in[4];
  const float* wv = (const float*)d_in[5];
  const float* bv = (const float*)d_in[6];
  const float* wo = (const float*)d_in[7];
  const float* bo = (const float*)d_in[8];
  float* out = (float*)d_out;

  const int M = B_SZ * T_SEQ;   // 4096
  const int N = D_MODEL;        // 1024
  const int K = D_MODEL;        // 1024

  unsigned short* qb = (unsigned short*)d_ws;          // bf16 [B*H, T, 64]  8 MiB
  unsigned short* kb = qb + (size_t)M * N;             // 8 MiB
  unsigned short* vb = kb + (size_t)M * N;             // 8 MiB
  float* attn = (float*)(vb + (size_t)M * N);          // fp32 [M, N] 16 MiB

  dim3 gblock(256);
  dim3 ggrid(M / 32, N / 32);
  gemm_bias_kernel<<<ggrid, gblock, 0, stream>>>(x, wq, bq, qb, M, N, K, 1);
  gemm_bias_kernel<<<ggrid, gblock, 0, stream>>>(x, wk, bk, kb, M, N, K, 1);
  gemm_bias_kernel<<<ggrid, gblock, 0, stream>>>(x, wv, bv, vb, M, N, K, 1);

  dim3 fgrid(T_SEQ / 64, B_SZ * N_HEADS);
  flash_kernel<<<fgrid, dim3(256), 0, stream>>>(qb, kb, vb, attn);

  gemm_bias_kernel<<<ggrid, gblock, 0, stream>>>(attn, wo, bo, out, M, N, K, 0);
}

// Round 3
// 365.733 us; speedup vs baseline: 12.9746x; 4.3283x over previous
//
#include <hip/hip_runtime.h>
#include <math.h>

#define D_MODEL 1024
#define N_HEADS 16
#define D_HEAD  64
#define B_SZ    2
#define T_SEQ   2048

typedef short bf16x8 __attribute__((ext_vector_type(8)));
typedef float f32x4  __attribute__((ext_vector_type(4)));
typedef unsigned short us4 __attribute__((ext_vector_type(4)));

// fp32 -> bf16 (RNE)
__device__ __forceinline__ unsigned short f2bf(float f) {
  union { float f; unsigned u; } v; v.f = f;
  unsigned r = v.u + 0x7FFFu + ((v.u >> 16) & 1u);
  return (unsigned short)(r >> 16);
}

// async global->LDS, 16B per lane. LDS dest = wave-uniform base + lane*16.
__device__ __forceinline__ void async_copy16(const unsigned short* g, unsigned short* l) {
  __builtin_amdgcn_global_load_lds(
      (__attribute__((address_space(1))) void*)(g),
      (__attribute__((address_space(3))) void*)(l), 16, 0, 0);
}

// ---------------------------------------------------------------------------
// x fp32 -> bf16 (same layout). grid*256*4 == elems
// ---------------------------------------------------------------------------
__global__ __launch_bounds__(256) void conv_x_kernel(
    const float* __restrict__ X, unsigned short* __restrict__ Y)
{
  size_t i = ((size_t)blockIdx.x * 256 + threadIdx.x) * 4;
  float4 v = *(const float4*)(X + i);
  us4 o = { f2bf(v.x), f2bf(v.y), f2bf(v.z), f2bf(v.w) };
  *(us4*)(Y + i) = o;
}

// ---------------------------------------------------------------------------
// W fp32 [K=1024, N=1024] -> Wt bf16 [N, K]; z selects {wq,wk,wv,wo}.
// ---------------------------------------------------------------------------
__global__ __launch_bounds__(256) void conv_w_kernel(
    const float* __restrict__ wq, const float* __restrict__ wk,
    const float* __restrict__ wv, const float* __restrict__ wo,
    unsigned short* __restrict__ out)
{
  const float* W = (blockIdx.z == 0) ? wq : (blockIdx.z == 1) ? wk
                 : (blockIdx.z == 2) ? wv : wo;
  unsigned short* O = out + (size_t)blockIdx.z * D_MODEL * D_MODEL;
  __shared__ float t[32][33];
  const int tx = threadIdx.x & 31, ty = threadIdx.x >> 5;
  const int kb = blockIdx.x * 32, nb = blockIdx.y * 32;
  #pragma unroll
  for (int i = 0; i < 4; i++)
    t[ty + i * 8][tx] = W[(size_t)(kb + ty + i * 8) * D_MODEL + nb + tx];
  __syncthreads();
  #pragma unroll
  for (int i = 0; i < 4; i++)
    O[(size_t)(nb + ty + i * 8) * D_MODEL + kb + tx] = f2bf(t[tx][ty + i * 8]);
}

// ---------------------------------------------------------------------------
// bf16 MFMA GEMM: C = A[M,K] @ Wt[N,K]^T + bias[N], fp32 accum.
// 128x128 tile, BK=64, 256 thr = 4 waves (2x2), each wave 64x64 = 4x4 MFMAs.
// Staging: global_load_lds 16B/lane; XOR chunk-swizzle (c ^ (row&7)) applied
// on the GLOBAL side so LDS stays linear; frag ds_read_b128 applies same xor.
// mode 0: fp32 C[m*N+n]; mode 1: bf16 scatter to [B*H, T, 64].
// ---------------------------------------------------------------------------
#define BKg 64

__global__ __launch_bounds__(256) void mfma_gemm(
    const unsigned short* __restrict__ A, const unsigned short* __restrict__ Bt,
    const float* __restrict__ bias, void* __restrict__ C,
    int M, int N, int K, int mode)
{
  __shared__ unsigned short As[128 * BKg];   // 16 KB
  __shared__ unsigned short Bs[128 * BKg];   // 16 KB

  const int tid  = threadIdx.x;
  const int wv   = tid >> 6;
  const int lane = tid & 63;
  const int lr   = lane & 15;
  const int quad = lane >> 4;
  const int wm   = wv >> 1;       // wave row 0..1
  const int wn   = wv & 1;        // wave col 0..1
  const int row0 = blockIdx.x * 128;
  const int col0 = blockIdx.y * 128;

  f32x4 acc[4][4];
  #pragma unroll
  for (int mi = 0; mi < 4; mi++)
    #pragma unroll
    for (int ni = 0; ni < 4; ni++) acc[mi][ni] = (f32x4){0.f, 0.f, 0.f, 0.f};

  for (int k0 = 0; k0 < K; k0 += BKg) {
    // ---- stage A,B tiles: 128 rows x 64 bf16 = 1024 chunks of 16B each ----
    #pragma unroll
    for (int it = 0; it < 4; it++) {
      const int gg = wv * 256 + it * 64 + lane;   // chunk id 0..1023
      const int r  = gg >> 3;                     // tile row
      const int cp = gg & 7;                      // LDS chunk within row
      const int gc = (cp ^ (r & 7)) * 8;          // swizzled global col (bf16)
      unsigned short* ldst = (unsigned short*)As + (size_t)(wv * 256 + it * 64) * 8;
      async_copy16(A  + (size_t)(row0 + r) * K + k0 + gc, ldst);
      unsigned short* ldstB = (unsigned short*)Bs + (size_t)(wv * 256 + it * 64) * 8;
      async_copy16(Bt + (size_t)(col0 + r) * K + k0 + gc, ldstB);
    }
    __syncthreads();   // drains vmcnt: staged data visible

    // ---- fragments (b128, xor-swizzled) ----
    bf16x8 aF[4][2], bF[4][2];
    #pragma unroll
    for (int mi = 0; mi < 4; mi++) {
      #pragma unroll
      for (int hf = 0; hf < 2; hf++) {
        const int kc = (hf * 4 + quad) ^ (lr & 7);
        aF[mi][hf] = *(const bf16x8*)&As[(wm * 64 + mi * 16 + lr) * BKg + kc * 8];
        bF[mi][hf] = *(const bf16x8*)&Bs[(wn * 64 + mi * 16 + lr) * BKg + kc * 8];
      }
    }
    #pragma unroll
    for (int hf = 0; hf < 2; hf++)
      #pragma unroll
      for (int mi = 0; mi < 4; mi++)
        #pragma unroll
        for (int ni = 0; ni < 4; ni++)
          acc[mi][ni] = __builtin_amdgcn_mfma_f32_16x16x32_bf16(
              aF[mi][hf], bF[ni][hf], acc[mi][ni], 0, 0, 0);
    __syncthreads();   // all reads done before next stage overwrites
  }

  // ---- epilogue ----
  #pragma unroll
  for (int ni = 0; ni < 4; ni++) {
    const int n = col0 + wn * 64 + ni * 16 + lr;
    const float bv = bias[n];
    #pragma unroll
    for (int mi = 0; mi < 4; mi++) {
      #pragma unroll
      for (int i = 0; i < 4; i++) {
        const int m = row0 + wm * 64 + mi * 16 + quad * 4 + i;
        const float val = acc[mi][ni][i] + bv;
        if (mode == 0) {
          ((float*)C)[(size_t)m * N + n] = val;
        } else {
          const int b = m >> 11, t = m & 2047;
          const int h = n >> 6,  d = n & 63;
          ((unsigned short*)C)[((size_t)(b * N_HEADS + h) * T_SEQ + t) * D_HEAD + d] = f2bf(val);
        }
      }
    }
  }
}

// ---------------------------------------------------------------------------
// MFMA flash attention (causal), bf16 in, bf16 out [B, T, H*64].
// ---------------------------------------------------------------------------
#define LDP 72

__global__ __launch_bounds__(256) void flash_kernel(
    const unsigned short* __restrict__ Q, const unsigned short* __restrict__ K,
    const unsigned short* __restrict__ V, unsigned short* __restrict__ Out)
{
  const int bh = blockIdx.y;
  const int q0 = blockIdx.x * 64;
  const int b  = bh / N_HEADS;
  const int h  = bh % N_HEADS;

  const unsigned short* Qb = Q + (size_t)bh * T_SEQ * D_HEAD;
  const unsigned short* Kb = K + (size_t)bh * T_SEQ * D_HEAD;
  const unsigned short* Vb = V + (size_t)bh * T_SEQ * D_HEAD;

  __shared__ __align__(16) unsigned short Qs[64][LDP];
  __shared__ __align__(16) unsigned short Ks[64][LDP];
  __shared__ __align__(16) unsigned short Vt[64][LDP];
  __shared__ __align__(16) unsigned short Ps[4][16][LDP];

  const int tid  = threadIdx.x;
  const int wv   = tid >> 6;
  const int lane = tid & 63;
  const int lr   = lane & 15;
  const int quad = lane >> 4;

  #pragma unroll
  for (int it = 0; it < 2; it++) {
    int t = tid + it * 256;
    int row = t >> 3, c8 = (t & 7) * 8;
    *(uint4*)&Qs[row][c8] = *(const uint4*)&Qb[(size_t)(q0 + row) * D_HEAD + c8];
  }
  __syncthreads();

  const bf16x8 aQ0 = *(const bf16x8*)&Qs[wv * 16 + lr][quad * 8];
  const bf16x8 aQ1 = *(const bf16x8*)&Qs[wv * 16 + lr][32 + quad * 8];

  f32x4 oacc[4];
  #pragma unroll
  for (int nt = 0; nt < 4; nt++) oacc[nt] = (f32x4){0.f, 0.f, 0.f, 0.f};
  float m_i[4] = {-INFINITY, -INFINITY, -INFINITY, -INFINITY};
  float l_i[4] = {0.f, 0.f, 0.f, 0.f};

  const float SCL2 = 0.125f * 1.44269504f;

  for (int j0 = 0; j0 <= q0; j0 += 64) {
    __syncthreads();

    #pragma unroll
    for (int it = 0; it < 2; it++) {
      int t = tid + it * 256;
      int row = t >> 3, c8 = (t & 7) * 8;
      *(uint4*)&Ks[row][c8] = *(const uint4*)&Kb[(size_t)(j0 + row) * D_HEAD + c8];
      union { uint4 u; unsigned short s[8]; } vvv;
      vvv.u = *(const uint4*)&Vb[(size_t)(j0 + row) * D_HEAD + c8];
      #pragma unroll
      for (int i = 0; i < 8; i++) Vt[c8 + i][row] = vvv.s[i];
    }
    __syncthreads();

    f32x4 sacc[4];
    #pragma unroll
    for (int nt = 0; nt < 4; nt++) {
      bf16x8 b0 = *(const bf16x8*)&Ks[nt * 16 + lr][quad * 8];
      bf16x8 b1 = *(const bf16x8*)&Ks[nt * 16 + lr][32 + quad * 8];
      f32x4 c = (f32x4){0.f, 0.f, 0.f, 0.f};
      c = __builtin_amdgcn_mfma_f32_16x16x32_bf16(aQ0, b0, c, 0, 0, 0);
      c = __builtin_amdgcn_mfma_f32_16x16x32_bf16(aQ1, b1, c, 0, 0, 0);
      sacc[nt] = c;
    }

    #pragma unroll
    for (int i = 0; i < 4; i++) {
      const int qrow = q0 + wv * 16 + quad * 4 + i;
      float z[4];
      float rm = -INFINITY;
      #pragma unroll
      for (int nt = 0; nt < 4; nt++) {
        float zz = sacc[nt][i] * SCL2;
        int kvc = j0 + nt * 16 + lr;
        zz = (kvc <= qrow) ? zz : -INFINITY;
        z[nt] = zz;
        rm = fmaxf(rm, zz);
      }
      rm = fmaxf(rm, __shfl_xor(rm, 1));
      rm = fmaxf(rm, __shfl_xor(rm, 2));
      rm = fmaxf(rm, __shfl_xor(rm, 4));
      rm = fmaxf(rm, __shfl_xor(rm, 8));
      const float mn = fmaxf(m_i[i], rm);
      const float alpha = exp2f(m_i[i] - mn);
      float rs = 0.f;
      #pragma unroll
      for (int nt = 0; nt < 4; nt++) {
        float p = exp2f(z[nt] - mn);
        rs += p;
        Ps[wv][quad * 4 + i][nt * 16 + lr] = f2bf(p);
      }
      rs += __shfl_xor(rs, 1);
      rs += __shfl_xor(rs, 2);
      rs += __shfl_xor(rs, 4);
      rs += __shfl_xor(rs, 8);
      l_i[i] = l_i[i] * alpha + rs;
      m_i[i] = mn;
      #pragma unroll
      for (int nt = 0; nt < 4; nt++) oacc[nt][i] *= alpha;
    }

    asm volatile("s_waitcnt lgkmcnt(0)" ::: "memory");

    const bf16x8 aP0 = *(const bf16x8*)&Ps[wv][lr][quad * 8];
    const bf16x8 aP1 = *(const bf16x8*)&Ps[wv][lr][32 + quad * 8];
    #pragma unroll
    for (int nt = 0; nt < 4; nt++) {
      bf16x8 b0 = *(const bf16x8*)&Vt[nt * 16 + lr][quad * 8];
      bf16x8 b1 = *(const bf16x8*)&Vt[nt * 16 + lr][32 + quad * 8];
      oacc[nt] = __builtin_amdgcn_mfma_f32_16x16x32_bf16(aP0, b0, oacc[nt], 0, 0, 0);
      oacc[nt] = __builtin_amdgcn_mfma_f32_16x16x32_bf16(aP1, b1, oacc[nt], 0, 0, 0);
    }
  }

  float invl[4];
  #pragma unroll
  for (int i = 0; i < 4; i++) invl[i] = 1.f / l_i[i];
  #pragma unroll
  for (int nt = 0; nt < 4; nt++) {
    const int d = nt * 16 + lr;
    #pragma unroll
    for (int i = 0; i < 4; i++) {
      const int q = q0 + wv * 16 + quad * 4 + i;
      Out[(size_t)(b * T_SEQ + q) * D_MODEL + h * D_HEAD + d] = f2bf(oacc[nt][i] * invl[i]);
    }
  }
}

// ---------------------------------------------------------------------------
extern "C" void kernel_launch(void* const* d_in, const int* in_sizes, int n_in,
                              void* d_out, int out_size, void* d_ws, size_t ws_size,
                              hipStream_t stream) {
  (void)in_sizes; (void)n_in; (void)out_size; (void)ws_size;

  const float* x  = (const float*)d_in[0];
  const float* wq = (const float*)d_in[1];
  const float* bq = (const float*)d_in[2];
  const float* wk = (const float*)d_in[3];
  const float* bk = (const float*)d_in[4];
  const float* wv = (const float*)d_in[5];
  const float* bv = (const float*)d_in[6];
  const float* wo = (const float*)d_in[7];
  const float* bo = (const float*)d_in[8];
  float* out = (float*)d_out;

  const int M = B_SZ * T_SEQ;   // 4096
  const int N = D_MODEL;        // 1024
  const int K = D_MODEL;        // 1024
  const size_t MN = (size_t)M * N;     // 4M elems
  const size_t WN = (size_t)N * N;     // 1M elems

  unsigned short* xb    = (unsigned short*)d_ws;       // bf16 [M,K]       8 MiB
  unsigned short* wt    = xb + MN;                     // bf16 4x[N,K]     8 MiB
  unsigned short* qb    = wt + 4 * WN;                 // bf16 [B*H,T,64]  8 MiB
  unsigned short* kb    = qb + MN;                     // 8 MiB
  unsigned short* vb    = kb + MN;                     // 8 MiB
  unsigned short* attnb = vb + MN;                     // bf16 [M,N]       8 MiB

  conv_x_kernel<<<dim3(M * K / 1024), dim3(256), 0, stream>>>(x, xb);
  conv_w_kernel<<<dim3(32, 32, 4), dim3(256), 0, stream>>>(wq, wk, wv, wo, wt);

  dim3 ggrid(M / 128, N / 128);
  mfma_gemm<<<ggrid, dim3(256), 0, stream>>>(xb, wt + 0 * WN, bq, qb, M, N, K, 1);
  mfma_gemm<<<ggrid, dim3(256), 0, stream>>>(xb, wt + 1 * WN, bk, kb, M, N, K, 1);
  mfma_gemm<<<ggrid, dim3(256), 0, stream>>>(xb, wt + 2 * WN, bv, vb, M, N, K, 1);

  flash_kernel<<<dim3(T_SEQ / 64, B_SZ * N_HEADS), dim3(256), 0, stream>>>(qb, kb, vb, attnb);

  mfma_gemm<<<ggrid, dim3(256), 0, stream>>>(attnb, wt + 3 * WN, bo, out, M, N, K, 0);
}

// Round 4
// 293.237 us; speedup vs baseline: 16.1823x; 1.2472x over previous
//
#include <hip/hip_runtime.h>
#include <math.h>

#define D_MODEL 1024
#define N_HEADS 16
#define D_HEAD  64
#define B_SZ    2
#define T_SEQ   2048

typedef short bf16x8 __attribute__((ext_vector_type(8)));
typedef float f32x4  __attribute__((ext_vector_type(4)));
typedef unsigned short us4 __attribute__((ext_vector_type(4)));

// fp32 -> bf16 (RNE)
__device__ __forceinline__ unsigned short f2bf(float f) {
  union { float f; unsigned u; } v; v.f = f;
  unsigned r = v.u + 0x7FFFu + ((v.u >> 16) & 1u);
  return (unsigned short)(r >> 16);
}

// async global->LDS, 16B per lane. LDS dest = wave-uniform base + lane*16.
__device__ __forceinline__ void async_copy16(const unsigned short* g, unsigned short* l) {
  __builtin_amdgcn_global_load_lds(
      (__attribute__((address_space(1))) void*)(g),
      (__attribute__((address_space(3))) void*)(l), 16, 0, 0);
}

// ---------------------------------------------------------------------------
// x fp32 -> bf16 (same layout). grid*256*4 == elems
// ---------------------------------------------------------------------------
__global__ __launch_bounds__(256) void conv_x_kernel(
    const float* __restrict__ X, unsigned short* __restrict__ Y)
{
  size_t i = ((size_t)blockIdx.x * 256 + threadIdx.x) * 4;
  float4 v = *(const float4*)(X + i);
  us4 o = { f2bf(v.x), f2bf(v.y), f2bf(v.z), f2bf(v.w) };
  *(us4*)(Y + i) = o;
}

// ---------------------------------------------------------------------------
// W fp32 [K=1024, N=1024] -> Wt bf16 [N, K]; z selects {wq,wk,wv,wo}.
// ---------------------------------------------------------------------------
__global__ __launch_bounds__(256) void conv_w_kernel(
    const float* __restrict__ wq, const float* __restrict__ wk,
    const float* __restrict__ wv, const float* __restrict__ wo,
    unsigned short* __restrict__ out)
{
  const float* W = (blockIdx.z == 0) ? wq : (blockIdx.z == 1) ? wk
                 : (blockIdx.z == 2) ? wv : wo;
  unsigned short* O = out + (size_t)blockIdx.z * D_MODEL * D_MODEL;
  __shared__ float t[32][33];
  const int tx = threadIdx.x & 31, ty = threadIdx.x >> 5;
  const int kb = blockIdx.x * 32, nb = blockIdx.y * 32;
  #pragma unroll
  for (int i = 0; i < 4; i++)
    t[ty + i * 8][tx] = W[(size_t)(kb + ty + i * 8) * D_MODEL + nb + tx];
  __syncthreads();
  #pragma unroll
  for (int i = 0; i < 4; i++)
    O[(size_t)(nb + ty + i * 8) * D_MODEL + kb + tx] = f2bf(t[tx][ty + i * 8]);
}

// ---------------------------------------------------------------------------
// vb bf16 [bh][T][64] -> vT bf16 [bh][64][T]   (per-bh 64x64-tile transpose)
// ---------------------------------------------------------------------------
__global__ __launch_bounds__(256) void transpose_v(
    const unsigned short* __restrict__ vb, unsigned short* __restrict__ vT)
{
  const int bh = blockIdx.y;
  const int t0 = blockIdx.x * 64;
  __shared__ unsigned short tile[64][72];
  const int tid = threadIdx.x;
  #pragma unroll
  for (int it = 0; it < 2; it++) {
    int idx = it * 256 + tid;
    int r = idx >> 3, c8 = (idx & 7) * 8;
    *(uint4*)&tile[r][c8] = *(const uint4*)&vb[((size_t)bh * T_SEQ + t0 + r) * D_HEAD + c8];
  }
  __syncthreads();
  #pragma unroll
  for (int it = 0; it < 2; it++) {
    int idx = it * 256 + tid;
    int d = idx >> 3, t8 = (idx & 7) * 8;
    us4 a, b;
    #pragma unroll
    for (int i = 0; i < 4; i++) a[i] = tile[t8 + i][d];
    #pragma unroll
    for (int i = 0; i < 4; i++) b[i] = tile[t8 + 4 + i][d];
    *(us4*)&vT[((size_t)bh * D_HEAD + d) * T_SEQ + t0 + t8] = a;
    *(us4*)&vT[((size_t)bh * D_HEAD + d) * T_SEQ + t0 + t8 + 4] = b;
  }
}

// ---------------------------------------------------------------------------
// bf16 MFMA GEMM: C = A[M,K] @ Wt[N,K]^T + bias[N], fp32 accum. (unchanged)
// ---------------------------------------------------------------------------
#define BKg 64

__global__ __launch_bounds__(256) void mfma_gemm(
    const unsigned short* __restrict__ A, const unsigned short* __restrict__ Bt,
    const float* __restrict__ bias, void* __restrict__ C,
    int M, int N, int K, int mode)
{
  __shared__ unsigned short As[128 * BKg];
  __shared__ unsigned short Bs[128 * BKg];

  const int tid  = threadIdx.x;
  const int wv   = tid >> 6;
  const int lane = tid & 63;
  const int lr   = lane & 15;
  const int quad = lane >> 4;
  const int wm   = wv >> 1;
  const int wn   = wv & 1;
  const int row0 = blockIdx.x * 128;
  const int col0 = blockIdx.y * 128;

  f32x4 acc[4][4];
  #pragma unroll
  for (int mi = 0; mi < 4; mi++)
    #pragma unroll
    for (int ni = 0; ni < 4; ni++) acc[mi][ni] = (f32x4){0.f, 0.f, 0.f, 0.f};

  for (int k0 = 0; k0 < K; k0 += BKg) {
    #pragma unroll
    for (int it = 0; it < 4; it++) {
      const int gg = wv * 256 + it * 64 + lane;
      const int r  = gg >> 3;
      const int cp = gg & 7;
      const int gc = (cp ^ (r & 7)) * 8;
      unsigned short* ldst = (unsigned short*)As + (size_t)(wv * 256 + it * 64) * 8;
      async_copy16(A  + (size_t)(row0 + r) * K + k0 + gc, ldst);
      unsigned short* ldstB = (unsigned short*)Bs + (size_t)(wv * 256 + it * 64) * 8;
      async_copy16(Bt + (size_t)(col0 + r) * K + k0 + gc, ldstB);
    }
    __syncthreads();

    bf16x8 aF[4][2], bF[4][2];
    #pragma unroll
    for (int mi = 0; mi < 4; mi++) {
      #pragma unroll
      for (int hf = 0; hf < 2; hf++) {
        const int kc = (hf * 4 + quad) ^ (lr & 7);
        aF[mi][hf] = *(const bf16x8*)&As[(wm * 64 + mi * 16 + lr) * BKg + kc * 8];
        bF[mi][hf] = *(const bf16x8*)&Bs[(wn * 64 + mi * 16 + lr) * BKg + kc * 8];
      }
    }
    #pragma unroll
    for (int hf = 0; hf < 2; hf++)
      #pragma unroll
      for (int mi = 0; mi < 4; mi++)
        #pragma unroll
        for (int ni = 0; ni < 4; ni++)
          acc[mi][ni] = __builtin_amdgcn_mfma_f32_16x16x32_bf16(
              aF[mi][hf], bF[ni][hf], acc[mi][ni], 0, 0, 0);
    __syncthreads();
  }

  #pragma unroll
  for (int ni = 0; ni < 4; ni++) {
    const int n = col0 + wn * 64 + ni * 16 + lr;
    const float bv = bias[n];
    #pragma unroll
    for (int mi = 0; mi < 4; mi++) {
      #pragma unroll
      for (int i = 0; i < 4; i++) {
        const int m = row0 + wm * 64 + mi * 16 + quad * 4 + i;
        const float val = acc[mi][ni][i] + bv;
        if (mode == 0) {
          ((float*)C)[(size_t)m * N + n] = val;
        } else {
          const int b = m >> 11, t = m & 2047;
          const int h = n >> 6,  d = n & 63;
          ((unsigned short*)C)[((size_t)(b * N_HEADS + h) * T_SEQ + t) * D_HEAD + d] = f2bf(val);
        }
      }
    }
  }
}

// ---------------------------------------------------------------------------
// Wave-independent MFMA flash attention (causal).
// Block = 64 threads = 1 wave, owns 32 Q rows (2 m-tiles of 16).
// Grid (32 bh, 64 qgroups). Zero __syncthreads: K/V frags direct from global
// (b128, L2-resident; bh -> fixed XCD via linear%8), P via per-wave LDS.
// ---------------------------------------------------------------------------
__global__ __launch_bounds__(64, 2) void flash_kernel(
    const unsigned short* __restrict__ Q, const unsigned short* __restrict__ K,
    const unsigned short* __restrict__ Vt, unsigned short* __restrict__ Out)
{
  const int bh = blockIdx.x;          // 0..31
  const int g  = blockIdx.y;          // 0..63
  const int q0 = g * 32;
  const int b  = bh >> 4;
  const int h  = bh & 15;

  const unsigned short* Qb = Q  + (size_t)bh * T_SEQ * D_HEAD;
  const unsigned short* Kb = K  + (size_t)bh * T_SEQ * D_HEAD;
  const unsigned short* Vb = Vt + (size_t)bh * D_HEAD * T_SEQ;   // [d][t]

  __shared__ __align__(16) unsigned short Ps[32][72];

  const int lane = threadIdx.x;
  const int lr   = lane & 15;
  const int quad = lane >> 4;

  // Q fragments (loop-invariant): A[m=lr][k=quad*8+j], two m-tiles, two k-halves
  bf16x8 aQ[2][2];
  #pragma unroll
  for (int mi = 0; mi < 2; mi++)
    #pragma unroll
    for (int kh = 0; kh < 2; kh++)
      aQ[mi][kh] = *(const bf16x8*)&Qb[(size_t)(q0 + mi * 16 + lr) * D_HEAD + kh * 32 + quad * 8];

  f32x4 oacc[2][4];
  float m_i[2][4], l_i[2][4];
  #pragma unroll
  for (int mi = 0; mi < 2; mi++) {
    #pragma unroll
    for (int nt = 0; nt < 4; nt++) oacc[mi][nt] = (f32x4){0.f, 0.f, 0.f, 0.f};
    #pragma unroll
    for (int i = 0; i < 4; i++) { m_i[mi][i] = -INFINITY; l_i[mi][i] = 0.f; }
  }

  const int ntiles = ((q0 + 31) >> 6) + 1;
  const float SCL2 = 0.125f * 1.44269504f;

  // preload K fragments for tile 0: B[k=quad*8+j][n=kv=nt*16+lr] = K[kv][d]
  bf16x8 bK[4][2];
  #pragma unroll
  for (int nt = 0; nt < 4; nt++)
    #pragma unroll
    for (int kh = 0; kh < 2; kh++)
      bK[nt][kh] = *(const bf16x8*)&Kb[(size_t)(nt * 16 + lr) * D_HEAD + kh * 32 + quad * 8];

  for (int j = 0; j < ntiles; j++) {
    const int kv0 = j * 64;

    // V fragments for current tile (issue now, consumed after softmax):
    // B[k=kv][n=d] -> vT[d][kv] contiguous along kv
    bf16x8 bV[4][2];
    #pragma unroll
    for (int nt = 0; nt < 4; nt++)
      #pragma unroll
      for (int kh = 0; kh < 2; kh++)
        bV[nt][kh] = *(const bf16x8*)&Vb[(size_t)(nt * 16 + lr) * T_SEQ + kv0 + kh * 32 + quad * 8];

    // ---- S = Q K^T ----
    f32x4 sacc[2][4];
    #pragma unroll
    for (int mi = 0; mi < 2; mi++)
      #pragma unroll
      for (int nt = 0; nt < 4; nt++) {
        f32x4 c = (f32x4){0.f, 0.f, 0.f, 0.f};
        c = __builtin_amdgcn_mfma_f32_16x16x32_bf16(aQ[mi][0], bK[nt][0], c, 0, 0, 0);
        c = __builtin_amdgcn_mfma_f32_16x16x32_bf16(aQ[mi][1], bK[nt][1], c, 0, 0, 0);
        sacc[mi][nt] = c;
      }

    // ---- prefetch next tile's K fragments during softmax ----
    bf16x8 nK[4][2];
    const bool hasNext = (j + 1 < ntiles);
    if (hasNext) {
      const int nk0 = kv0 + 64;
      #pragma unroll
      for (int nt = 0; nt < 4; nt++)
        #pragma unroll
        for (int kh = 0; kh < 2; kh++)
          nK[nt][kh] = *(const bf16x8*)&Kb[(size_t)(nk0 + nt * 16 + lr) * D_HEAD + kh * 32 + quad * 8];
    }

    // ---- online softmax (exp2 domain) ----
    const bool diag = (kv0 + 64 > q0);
    #pragma unroll
    for (int mi = 0; mi < 2; mi++) {
      #pragma unroll
      for (int i = 0; i < 4; i++) {
        const int row = q0 + mi * 16 + quad * 4 + i;
        float z[4];
        float rm = -INFINITY;
        #pragma unroll
        for (int nt = 0; nt < 4; nt++) {
          float zz = sacc[mi][nt][i] * SCL2;
          if (diag && (kv0 + nt * 16 + lr > row)) zz = -INFINITY;
          z[nt] = zz;
          rm = fmaxf(rm, zz);
        }
        rm = fmaxf(rm, __shfl_xor(rm, 1));
        rm = fmaxf(rm, __shfl_xor(rm, 2));
        rm = fmaxf(rm, __shfl_xor(rm, 4));
        rm = fmaxf(rm, __shfl_xor(rm, 8));
        const float mn = fmaxf(m_i[mi][i], rm);
        const float alpha = exp2f(m_i[mi][i] - mn);
        float rs = 0.f;
        #pragma unroll
        for (int nt = 0; nt < 4; nt++) {
          float p = exp2f(z[nt] - mn);
          rs += p;
          Ps[mi * 16 + quad * 4 + i][nt * 16 + lr] = f2bf(p);
        }
        rs += __shfl_xor(rs, 1);
        rs += __shfl_xor(rs, 2);
        rs += __shfl_xor(rs, 4);
        rs += __shfl_xor(rs, 8);
        l_i[mi][i] = l_i[mi][i] * alpha + rs;
        m_i[mi][i] = mn;
        #pragma unroll
        for (int nt = 0; nt < 4; nt++) oacc[mi][nt][i] *= alpha;
      }
    }

    // wave-local fence: Ps writes visible to this wave's reads
    asm volatile("s_waitcnt lgkmcnt(0)" ::: "memory");

    // ---- O += P V ----
    bf16x8 aP[2][2];
    #pragma unroll
    for (int mi = 0; mi < 2; mi++)
      #pragma unroll
      for (int kh = 0; kh < 2; kh++)
        aP[mi][kh] = *(const bf16x8*)&Ps[mi * 16 + lr][kh * 32 + quad * 8];

    #pragma unroll
    for (int mi = 0; mi < 2; mi++)
      #pragma unroll
      for (int nt = 0; nt < 4; nt++) {
        oacc[mi][nt] = __builtin_amdgcn_mfma_f32_16x16x32_bf16(aP[mi][0], bV[nt][0], oacc[mi][nt], 0, 0, 0);
        oacc[mi][nt] = __builtin_amdgcn_mfma_f32_16x16x32_bf16(aP[mi][1], bV[nt][1], oacc[mi][nt], 0, 0, 0);
      }

    if (hasNext) {
      #pragma unroll
      for (int nt = 0; nt < 4; nt++)
        #pragma unroll
        for (int kh = 0; kh < 2; kh++)
          bK[nt][kh] = nK[nt][kh];
    }
  }

  // ---- epilogue: bf16 Out[b*T + row][h*64 + d] ----
  #pragma unroll
  for (int mi = 0; mi < 2; mi++) {
    #pragma unroll
    for (int i = 0; i < 4; i++) {
      const float invl = 1.f / l_i[mi][i];
      const int row = q0 + mi * 16 + quad * 4 + i;
      #pragma unroll
      for (int nt = 0; nt < 4; nt++) {
        Out[(size_t)(b * T_SEQ + row) * D_MODEL + h * D_HEAD + nt * 16 + lr] =
            f2bf(oacc[mi][nt][i] * invl);
      }
    }
  }
}

// ---------------------------------------------------------------------------
extern "C" void kernel_launch(void* const* d_in, const int* in_sizes, int n_in,
                              void* d_out, int out_size, void* d_ws, size_t ws_size,
                              hipStream_t stream) {
  (void)in_sizes; (void)n_in; (void)out_size; (void)ws_size;

  const float* x  = (const float*)d_in[0];
  const float* wq = (const float*)d_in[1];
  const float* bq = (const float*)d_in[2];
  const float* wk = (const float*)d_in[3];
  const float* bk = (const float*)d_in[4];
  const float* wv = (const float*)d_in[5];
  const float* bv = (const float*)d_in[6];
  const float* wo = (const float*)d_in[7];
  const float* bo = (const float*)d_in[8];
  float* out = (float*)d_out;

  const int M = B_SZ * T_SEQ;   // 4096
  const int N = D_MODEL;        // 1024
  const int K = D_MODEL;        // 1024
  const size_t MN = (size_t)M * N;
  const size_t WN = (size_t)N * N;

  unsigned short* xb    = (unsigned short*)d_ws;       // bf16 [M,K]       8 MiB
  unsigned short* wt    = xb + MN;                     // bf16 4x[N,K]     8 MiB
  unsigned short* qb    = wt + 4 * WN;                 // bf16 [B*H,T,64]  8 MiB
  unsigned short* kb    = qb + MN;                     // 8 MiB
  unsigned short* vb    = kb + MN;                     // 8 MiB
  unsigned short* vT    = vb + MN;                     // bf16 [B*H,64,T]  8 MiB
  unsigned short* attnb = vT + MN;                     // bf16 [M,N]       8 MiB

  conv_x_kernel<<<dim3(M * K / 1024), dim3(256), 0, stream>>>(x, xb);
  conv_w_kernel<<<dim3(32, 32, 4), dim3(256), 0, stream>>>(wq, wk, wv, wo, wt);

  dim3 ggrid(M / 128, N / 128);
  mfma_gemm<<<ggrid, dim3(256), 0, stream>>>(xb, wt + 0 * WN, bq, qb, M, N, K, 1);
  mfma_gemm<<<ggrid, dim3(256), 0, stream>>>(xb, wt + 1 * WN, bk, kb, M, N, K, 1);
  mfma_gemm<<<ggrid, dim3(256), 0, stream>>>(xb, wt + 2 * WN, bv, vb, M, N, K, 1);

  transpose_v<<<dim3(T_SEQ / 64, B_SZ * N_HEADS), dim3(256), 0, stream>>>(vb, vT);

  flash_kernel<<<dim3(B_SZ * N_HEADS, T_SEQ / 32), dim3(64), 0, stream>>>(qb, kb, vT, attnb);

  mfma_gemm<<<ggrid, dim3(256), 0, stream>>>(attnb, wt + 3 * WN, bo, out, M, N, K, 0);
}